// Round 11
// baseline (246.281 us; speedup 1.0000x reference)
//
#include <hip/hip_runtime.h>
#include <stdint.h>

#define NB    1024
#define IL    4096
#define NOUT  4096
#define FI    128
#define BTILE 8
#define OSPLIT 4
#define OTILE (NOUT / OSPLIT)        // 1024 outputs per block
#define SLAB_DW (IL * (BTILE / 2))   // 16384 dwords = 64KB per batch-group slab
#define SLAB_BLOCKS ((NB / BTILE) * IL / 256)   // 2048
#define SORT_BLOCKS (NOUT / 4)                  // 1024 (wave per row)

__device__ __forceinline__ uint32_t rne_bf16_hi(float x) {
  uint32_t u = __float_as_uint(x);
  u += 0x7FFFu + ((u >> 16) & 1u);
  return u & 0xFFFF0000u;
}

// merged pre-pass: slab build + comb-sorted pack (see R10)
__global__ __launch_bounds__(256)
void prep_kernel(const float* __restrict__ in, uint32_t* __restrict__ slab,
                 const int* __restrict__ idx, const float* __restrict__ w,
                 uint32_t* __restrict__ pack) {
  const int bid = blockIdx.x;
  if (bid < SLAB_BLOCKS) {
    int t = bid * 256 + threadIdx.x;
    int g = t >> 12;
    int i = t & (IL - 1);
    const float* base = in + (size_t)g * (8 * IL) + i;
    uint4 v;
    v.x = rne_bf16_hi(base[1 * IL]) | (rne_bf16_hi(base[0 * IL]) >> 16);
    v.y = rne_bf16_hi(base[3 * IL]) | (rne_bf16_hi(base[2 * IL]) >> 16);
    v.z = rne_bf16_hi(base[5 * IL]) | (rne_bf16_hi(base[4 * IL]) >> 16);
    v.w = rne_bf16_hi(base[7 * IL]) | (rne_bf16_hi(base[6 * IL]) >> 16);
    reinterpret_cast<uint4*>(slab)[t] = v;
  } else {
    const int o = (bid - SLAB_BLOCKS) * 4 + (threadIdx.x >> 6);
    const unsigned lane = threadIdx.x & 63u;
    const uint32_t r = (uint32_t)(o & 7);
    const int*   irow = idx + (size_t)o * FI;
    const float* wrow = w   + (size_t)o * FI;
    uint32_t* prow = pack + (size_t)o * FI;

    uint32_t i0 = (uint32_t)irow[lane], i1 = (uint32_t)irow[64 + lane];
    uint32_t w0 = rne_bf16_hi(wrow[lane]), w1 = rne_bf16_hi(wrow[64 + lane]);
    uint32_t k0 = i0 & 7u, k1 = i1 & 7u;
    const uint64_t lt = (1ull << lane) - 1ull;

    uint32_t rank0 = 0, rank1 = 0;
    uint64_t cntp = 0;
    #pragma unroll
    for (int g = 0; g < 8; ++g) {
      uint64_t b0 = __ballot(k0 == (uint32_t)g);
      uint64_t b1 = __ballot(k1 == (uint32_t)g);
      uint32_t c0 = (uint32_t)__popcll(b0);
      if (k0 == (uint32_t)g) rank0 = (uint32_t)__popcll(b0 & lt);
      if (k1 == (uint32_t)g) rank1 = c0 + (uint32_t)__popcll(b1 & lt);
      cntp |= (uint64_t)(c0 + (uint32_t)__popcll(b1)) << (8 * g);
    }
    uint64_t ov0 = __ballot(rank0 >= 16u);
    uint64_t ov1 = __ballot(rank1 >= 16u);
    uint32_t ofr0 = (uint32_t)__popcll(ov0 & lt);
    uint32_t ofr1 = (uint32_t)__popcll(ov0) + (uint32_t)__popcll(ov1 & lt);

    auto place = [&](uint32_t k, uint32_t rank, uint32_t ofr) -> uint32_t {
      if (rank < 16u) return ((k - r) & 7u) + 8u * rank;
      uint32_t cum = 0, p = 0;
      bool done = false;
      #pragma unroll
      for (int lc = 0; lc < 8; ++lc) {
        uint32_t gl = ((uint32_t)lc + r) & 7u;
        uint32_t c  = (uint32_t)((cntp >> (8 * gl)) & 0xFFu);
        uint32_t u  = c < 16u ? c : 16u;
        uint32_t lcnt = 16u - u;
        if (!done && ofr < cum + lcnt) { p = (uint32_t)lc + 8u * (u + ofr - cum); done = true; }
        cum += lcnt;
      }
      return p;
    };
    prow[place(k0, rank0, ofr0)] = w0 | ((i0 << 4) & 0xFFFFu);
    prow[place(k1, rank1, ofr1)] = w1 | ((i1 << 4) & 0xFFFFu);
  }
}

// ABLATION VARIANTS:
// V=0 full (stores d_out) | V=1 no-DS (fabricated g, full VALU) |
// V=2 seq-DS (linear 0-conflict offsets, real FMAs) | V=3 DS-only (sink g, no FMA)
template<int V>
__global__ __launch_bounds__(1024)
void lincond_kernel(const uint32_t* __restrict__ slab,
                    const uint32_t* __restrict__ pack,
                    const float* __restrict__ bias,
                    float* __restrict__ out) {
  __shared__ uint32_t lds[SLAB_DW];
  const int bid   = blockIdx.x;
  const int b0    = (bid >> 2) * BTILE;
  const int obase = (bid & 3) * OTILE;
  const int tid   = threadIdx.x;

  const uint32_t* src = slab + (size_t)(b0 >> 3) * SLAB_DW;
  #pragma unroll
  for (int r = 0; r < 4; ++r) {
    int e = (r * 1024 + tid) * 4;
    __builtin_amdgcn_global_load_lds(
        (const __attribute__((address_space(1))) uint32_t*)(src + e),
        (__attribute__((address_space(3))) uint32_t*)(lds + e),
        16, 0, 0);
  }
  __syncthreads();

  const int o = obase + tid;
  const char* ldsb = reinterpret_cast<const char*>(lds);
  float acc[8] = {0.f,0.f,0.f,0.f,0.f,0.f,0.f,0.f};
  const uint4* pw = reinterpret_cast<const uint4*>(pack) + (size_t)o * (FI / 4);

  #pragma unroll 2
  for (int j = 0; j < 8; ++j) {
    uint4 pq[4];
    #pragma unroll
    for (int q = 0; q < 4; ++q) pq[q] = pw[j * 4 + q];
    #pragma unroll
    for (int q = 0; q < 4; ++q) {
      uint32_t pv4[4] = {pq[q].x, pq[q].y, pq[q].z, pq[q].w};
      #pragma unroll
      for (int c = 0; c < 4; ++c) {
        uint32_t pv = pv4[c];
        uint32_t off;
        if (V == 2) {
          int step = j * 16 + q * 4 + c;
          off = (uint32_t)(((step * 64 + (tid & 63)) & 4095) << 4);  // linear: 0-conflict
        } else {
          off = pv & 0xFFFFu;
        }
        uint4 g;
        if (V == 1) {  // fabricate in-register (no LDS access)
          g.x = off + pv; g.y = off ^ pv; g.z = off - pv; g.w = off + (pv >> 1);
        } else {
          g = *reinterpret_cast<const uint4*>(ldsb + off);
        }
        if (V == 3) {
          asm volatile("" :: "v"(g.x), "v"(g.y), "v"(g.z), "v"(g.w));
        } else {
          float wv = __uint_as_float(pv & 0xFFFF0000u);
          acc[0] = fmaf(wv, __uint_as_float(g.x << 16),         acc[0]);
          acc[1] = fmaf(wv, __uint_as_float(g.x & 0xFFFF0000u), acc[1]);
          acc[2] = fmaf(wv, __uint_as_float(g.y << 16),         acc[2]);
          acc[3] = fmaf(wv, __uint_as_float(g.y & 0xFFFF0000u), acc[3]);
          acc[4] = fmaf(wv, __uint_as_float(g.z << 16),         acc[4]);
          acc[5] = fmaf(wv, __uint_as_float(g.z & 0xFFFF0000u), acc[5]);
          acc[6] = fmaf(wv, __uint_as_float(g.w << 16),         acc[6]);
          acc[7] = fmaf(wv, __uint_as_float(g.w & 0xFFFF0000u), acc[7]);
        }
      }
    }
  }

  if (V == 0) {
    const float bv = bias[o];
    #pragma unroll
    for (int k = 0; k < 8; ++k)
      out[(size_t)(b0 + k) * NOUT + o] = acc[k] + bv;
  } else if (V != 3) {
    asm volatile("" :: "v"(acc[0]), "v"(acc[1]), "v"(acc[2]), "v"(acc[3]),
                       "v"(acc[4]), "v"(acc[5]), "v"(acc[6]), "v"(acc[7]));
  }
}

// fallback (never expected to run: ws has been sufficient every round)
__global__ __launch_bounds__(256)
void lincond_raw(const float* __restrict__ input, const float* __restrict__ wgt,
                 const float* __restrict__ bias, const int* __restrict__ idxs,
                 float* __restrict__ out) {
  int t = blockIdx.x * 256 + threadIdx.x;   // t = b*NOUT + o
  int b = t >> 12, o = t & (NOUT - 1);
  const float* irow = input + (size_t)b * IL;
  const int*   ix   = idxs + (size_t)o * FI;
  const float* wr   = wgt  + (size_t)o * FI;
  float acc = bias[o];
  for (int f = 0; f < FI; ++f) acc += wr[f] * irow[ix[f]];
  out[t] = acc;
}

extern "C" void kernel_launch(void* const* d_in, const int* in_sizes, int n_in,
                              void* d_out, int out_size, void* d_ws, size_t ws_size,
                              hipStream_t stream) {
  const float* input  = (const float*)d_in[0];
  const float* weight = (const float*)d_in[1];
  const float* bias   = (const float*)d_in[2];
  const int*   idxs   = (const int*)d_in[3];
  float*       out    = (float*)d_out;

  const size_t pack_bytes = (size_t)NOUT * FI * sizeof(uint32_t);              // 2 MB
  const size_t slab_bytes = (size_t)(NB / BTILE) * SLAB_DW * sizeof(uint32_t); // 8 MB
  const int grid = (NB / BTILE) * OSPLIT;                                      // 512

  if (ws_size >= pack_bytes + slab_bytes) {
    uint32_t* pack = (uint32_t*)d_ws;
    uint32_t* slab = (uint32_t*)((char*)d_ws + pack_bytes);
    prep_kernel<<<SLAB_BLOCKS + SORT_BLOCKS, 256, 0, stream>>>(input, slab, idxs, weight, pack);
    lincond_kernel<0><<<grid, 1024, 0, stream>>>(slab, pack, bias, out);  // real
    lincond_kernel<3><<<grid, 1024, 0, stream>>>(slab, pack, bias, out);  // DS-only
    lincond_kernel<2><<<grid, 1024, 0, stream>>>(slab, pack, bias, out);  // 0-conflict
    lincond_kernel<1><<<grid, 1024, 0, stream>>>(slab, pack, bias, out);  // no-DS
  } else {
    lincond_raw<<<(NB * NOUT) / 256, 256, 0, stream>>>(input, weight, bias, idxs, out);
  }
}

// Round 12
// 55.575 us; speedup vs baseline: 4.4315x; 4.4315x over previous
//
#include <hip/hip_runtime.h>
#include <stdint.h>

#define NB    1024
#define IL    4096
#define NOUT  4096
#define FI    128
#define BTILE 8
#define OSPLIT 4
#define OTILE (NOUT / OSPLIT)        // 1024 outputs per block
#define SLAB_DW (IL * (BTILE / 2))   // 16384 dwords = 64KB per batch-group slab
#define SLAB_BLOCKS ((NB / BTILE) * IL / 256)   // 2048
#define SORT_BLOCKS (NOUT / 4)                  // 1024 (wave per row)

__device__ __forceinline__ uint32_t rne_bf16_hi(float x) {
  uint32_t u = __float_as_uint(x);
  u += 0x7FFFu + ((u >> 16) & 1u);
  return u & 0xFFFF0000u;
}

// merged pre-pass: slab build + comb-sorted pack (unchanged from R10)
__global__ __launch_bounds__(256)
void prep_kernel(const float* __restrict__ in, uint32_t* __restrict__ slab,
                 const int* __restrict__ idx, const float* __restrict__ w,
                 uint32_t* __restrict__ pack) {
  const int bid = blockIdx.x;
  if (bid < SLAB_BLOCKS) {
    int t = bid * 256 + threadIdx.x;
    int g = t >> 12;
    int i = t & (IL - 1);
    const float* base = in + (size_t)g * (8 * IL) + i;
    uint4 v;
    v.x = rne_bf16_hi(base[1 * IL]) | (rne_bf16_hi(base[0 * IL]) >> 16);
    v.y = rne_bf16_hi(base[3 * IL]) | (rne_bf16_hi(base[2 * IL]) >> 16);
    v.z = rne_bf16_hi(base[5 * IL]) | (rne_bf16_hi(base[4 * IL]) >> 16);
    v.w = rne_bf16_hi(base[7 * IL]) | (rne_bf16_hi(base[6 * IL]) >> 16);
    reinterpret_cast<uint4*>(slab)[t] = v;
  } else {
    const int o = (bid - SLAB_BLOCKS) * 4 + (threadIdx.x >> 6);
    const unsigned lane = threadIdx.x & 63u;
    const uint32_t r = (uint32_t)(o & 7);
    const int*   irow = idx + (size_t)o * FI;
    const float* wrow = w   + (size_t)o * FI;
    uint32_t* prow = pack + (size_t)o * FI;

    uint32_t i0 = (uint32_t)irow[lane], i1 = (uint32_t)irow[64 + lane];
    uint32_t w0 = rne_bf16_hi(wrow[lane]), w1 = rne_bf16_hi(wrow[64 + lane]);
    uint32_t k0 = i0 & 7u, k1 = i1 & 7u;
    const uint64_t lt = (1ull << lane) - 1ull;

    uint32_t rank0 = 0, rank1 = 0;
    uint64_t cntp = 0;
    #pragma unroll
    for (int g = 0; g < 8; ++g) {
      uint64_t b0 = __ballot(k0 == (uint32_t)g);
      uint64_t b1 = __ballot(k1 == (uint32_t)g);
      uint32_t c0 = (uint32_t)__popcll(b0);
      if (k0 == (uint32_t)g) rank0 = (uint32_t)__popcll(b0 & lt);
      if (k1 == (uint32_t)g) rank1 = c0 + (uint32_t)__popcll(b1 & lt);
      cntp |= (uint64_t)(c0 + (uint32_t)__popcll(b1)) << (8 * g);
    }
    uint64_t ov0 = __ballot(rank0 >= 16u);
    uint64_t ov1 = __ballot(rank1 >= 16u);
    uint32_t ofr0 = (uint32_t)__popcll(ov0 & lt);
    uint32_t ofr1 = (uint32_t)__popcll(ov0) + (uint32_t)__popcll(ov1 & lt);

    auto place = [&](uint32_t k, uint32_t rank, uint32_t ofr) -> uint32_t {
      if (rank < 16u) return ((k - r) & 7u) + 8u * rank;
      uint32_t cum = 0, p = 0;
      bool done = false;
      #pragma unroll
      for (int lc = 0; lc < 8; ++lc) {
        uint32_t gl = ((uint32_t)lc + r) & 7u;
        uint32_t c  = (uint32_t)((cntp >> (8 * gl)) & 0xFFu);
        uint32_t u  = c < 16u ? c : 16u;
        uint32_t lcnt = 16u - u;
        if (!done && ofr < cum + lcnt) { p = (uint32_t)lc + 8u * (u + ofr - cum); done = true; }
        cum += lcnt;
      }
      return p;
    };
    prow[place(k0, rank0, ofr0)] = w0 | ((i0 << 4) & 0xFFFFu);
    prow[place(k1, rank1, ofr1)] = w1 | ((i1 << 4) & 0xFFFFu);
  }
}

// main kernel: DMA staging + chunked deep-batch gather loop.
// Per 16-gather chunk: prefetch 16 pack words, then 2 half-chunks of
// {8 independent ds_read_b128 -> g[0..7]} followed by 64 FMAs, so the
// compiler issues 8 loads back-to-back and consumes under counted lgkmcnt.
__global__ __launch_bounds__(1024)
void lincond_kernel(const uint32_t* __restrict__ slab,
                    const uint32_t* __restrict__ pack,
                    const float* __restrict__ bias,
                    float* __restrict__ out) {
  __shared__ uint32_t lds[SLAB_DW];   // 64 KB
  const int bid   = blockIdx.x;
  const int b0    = (bid >> 2) * BTILE;
  const int obase = (bid & 3) * OTILE;
  const int tid   = threadIdx.x;

  const uint32_t* src = slab + (size_t)(b0 >> 3) * SLAB_DW;
  #pragma unroll
  for (int r = 0; r < 4; ++r) {
    int e = (r * 1024 + tid) * 4;
    __builtin_amdgcn_global_load_lds(
        (const __attribute__((address_space(1))) uint32_t*)(src + e),
        (__attribute__((address_space(3))) uint32_t*)(lds + e),
        16, 0, 0);
  }
  __syncthreads();

  const int o = obase + tid;
  const char* ldsb = reinterpret_cast<const char*>(lds);
  float acc[8] = {0.f,0.f,0.f,0.f,0.f,0.f,0.f,0.f};
  const uint4* pw = reinterpret_cast<const uint4*>(pack) + (size_t)o * (FI / 4);

  #pragma unroll 2
  for (int j = 0; j < 8; ++j) {
    uint4 pq[4];
    #pragma unroll
    for (int q = 0; q < 4; ++q) pq[q] = pw[j * 4 + q];
    uint32_t pvw[16];
    #pragma unroll
    for (int q = 0; q < 4; ++q) {
      pvw[q * 4 + 0] = pq[q].x; pvw[q * 4 + 1] = pq[q].y;
      pvw[q * 4 + 2] = pq[q].z; pvw[q * 4 + 3] = pq[q].w;
    }
    #pragma unroll
    for (int h = 0; h < 2; ++h) {
      uint4 g[8];
      #pragma unroll
      for (int c = 0; c < 8; ++c)
        g[c] = *reinterpret_cast<const uint4*>(ldsb + (pvw[h * 8 + c] & 0xFFFFu));
      #pragma unroll
      for (int c = 0; c < 8; ++c) {
        float wv = __uint_as_float(pvw[h * 8 + c] & 0xFFFF0000u);
        acc[0] = fmaf(wv, __uint_as_float(g[c].x << 16),         acc[0]);
        acc[1] = fmaf(wv, __uint_as_float(g[c].x & 0xFFFF0000u), acc[1]);
        acc[2] = fmaf(wv, __uint_as_float(g[c].y << 16),         acc[2]);
        acc[3] = fmaf(wv, __uint_as_float(g[c].y & 0xFFFF0000u), acc[3]);
        acc[4] = fmaf(wv, __uint_as_float(g[c].z << 16),         acc[4]);
        acc[5] = fmaf(wv, __uint_as_float(g[c].z & 0xFFFF0000u), acc[5]);
        acc[6] = fmaf(wv, __uint_as_float(g[c].w << 16),         acc[6]);
        acc[7] = fmaf(wv, __uint_as_float(g[c].w & 0xFFFF0000u), acc[7]);
      }
    }
  }

  const float bv = bias[o];
  #pragma unroll
  for (int k = 0; k < 8; ++k)
    out[(size_t)(b0 + k) * NOUT + o] = acc[k] + bv;
}

// fallback (no workspace): naive but correct
__global__ __launch_bounds__(256)
void lincond_raw(const float* __restrict__ input, const float* __restrict__ wgt,
                 const float* __restrict__ bias, const int* __restrict__ idxs,
                 float* __restrict__ out) {
  int t = blockIdx.x * 256 + threadIdx.x;   // t = b*NOUT + o
  int b = t >> 12, o = t & (NOUT - 1);
  const float* irow = input + (size_t)b * IL;
  const int*   ix   = idxs + (size_t)o * FI;
  const float* wr   = wgt  + (size_t)o * FI;
  float acc = bias[o];
  for (int f = 0; f < FI; ++f) acc += wr[f] * irow[ix[f]];
  out[t] = acc;
}

extern "C" void kernel_launch(void* const* d_in, const int* in_sizes, int n_in,
                              void* d_out, int out_size, void* d_ws, size_t ws_size,
                              hipStream_t stream) {
  const float* input  = (const float*)d_in[0];
  const float* weight = (const float*)d_in[1];
  const float* bias   = (const float*)d_in[2];
  const int*   idxs   = (const int*)d_in[3];
  float*       out    = (float*)d_out;

  const size_t pack_bytes = (size_t)NOUT * FI * sizeof(uint32_t);              // 2 MB
  const size_t slab_bytes = (size_t)(NB / BTILE) * SLAB_DW * sizeof(uint32_t); // 8 MB
  const int grid = (NB / BTILE) * OSPLIT;                                      // 512

  if (ws_size >= pack_bytes + slab_bytes) {
    uint32_t* pack = (uint32_t*)d_ws;
    uint32_t* slab = (uint32_t*)((char*)d_ws + pack_bytes);
    prep_kernel<<<SLAB_BLOCKS + SORT_BLOCKS, 256, 0, stream>>>(input, slab, idxs, weight, pack);
    lincond_kernel<<<grid, 1024, 0, stream>>>(slab, pack, bias, out);
  } else {
    lincond_raw<<<(NB * NOUT) / 256, 256, 0, stream>>>(input, weight, bias, idxs, out);
  }
}